// Round 1
// baseline (185.416 us; speedup 1.0000x reference)
//
#include <hip/hip_runtime.h>
#include <hip/hip_bf16.h>

// Problem constants
#define HB 1024   // NUM_BASIC (GEMM K)
#define HM 8192   // NUM_MIXED (GEMM M)
#define NR 735    // 105*7 actual GEMM N
#define NPAD 768  // padded N (6 tiles of 128)
#define NOUT 57   // output is (HM, 57, 57)

typedef __attribute__((ext_vector_type(8))) _Float16 half8;
typedef __attribute__((ext_vector_type(4))) _Float16 half4v;
typedef __attribute__((ext_vector_type(4))) float floatx4;

// ---------------------------------------------------------------------------
// Kernel 1: build x2[r][h] = relu(te[h,t]*mat[h,n,m]) as fp16, padded to 768
// rows (zeros), K(h)-contiguous so GEMM B-operand is K-major.
// r = (t*7+m)*7 + n
// ---------------------------------------------------------------------------
__global__ __launch_bounds__(256) void prep_x2_kernel(
    const float* __restrict__ mat, const float* __restrict__ tex,
    _Float16* __restrict__ Xh) {
  const int r = blockIdx.x;
  const int n = r % 7;
  const int tm = r / 7;
  const int m = tm % 7;
  const int t = tm / 7;
#pragma unroll
  for (int i = 0; i < 4; ++i) {
    const int h = i * 256 + threadIdx.x;
    float v = 0.f;
    if (r < NR) {
      const float mv = mat[h * 49 + n * 7 + m];
      const float te = 1.f / (1.f + expf(-tex[h * 15 + t])) + 1.f;
      v = te * mv;
      v = v > 0.f ? v : 0.f;  // relu
    }
    Xh[r * HB + h] = (_Float16)v;
  }
}

// ---------------------------------------------------------------------------
// Kernel 2: W fp32 -> fp16 (halves GEMM staging bytes; W re-read 6x is
// L3-resident at 16.8 MB)
// ---------------------------------------------------------------------------
__global__ __launch_bounds__(256) void prep_w_kernel(
    const float4* __restrict__ W, half4v* __restrict__ Wh) {
  const int idx = blockIdx.x * 256 + threadIdx.x;
  const float4 v = W[idx];
  half4v h;
  h.x = (_Float16)v.x;
  h.y = (_Float16)v.y;
  h.z = (_Float16)v.z;
  h.w = (_Float16)v.w;
  Wh[idx] = h;
}

// ---------------------------------------------------------------------------
// Kernel 3: GEMM  Y[j][r] = relu( sum_h Wh[j][h]*Xh[r][h] + b[j] )
// M=8192, N=768(padded), K=1024. 128x128 block tile, BK=32,
// 4 waves each computing 64x64 via 4x4 grid of 16x16x32 f16 MFMAs.
// Staging: global_load_lds width=16 (wave-uniform LDS base + lane*16).
// ---------------------------------------------------------------------------
__global__ __launch_bounds__(256) void gemm_kernel(
    const _Float16* __restrict__ A,  // Wh [8192][1024]
    const _Float16* __restrict__ B,  // Xh [768][1024]
    const float* __restrict__ bias,  // [8192]
    float* __restrict__ Y) {         // [8192][768]
  __shared__ __align__(16) _Float16 As[128 * 32];
  __shared__ __align__(16) _Float16 Bs[128 * 32];

  const int tid = threadIdx.x;
  const int lane = tid & 63;
  const int wave = tid >> 6;
  const int bm = blockIdx.x;  // 64 tiles
  const int bn = blockIdx.y;  // 6 tiles
  const int wm = (wave >> 1) * 64;
  const int wn = (wave & 1) * 64;

  floatx4 acc[4][4] = {};

  // staging decomposition: 8 chunks of 1KB per 8KB tile; wave handles
  // chunks {2w, 2w+1}. lane l of chunk c covers LDS bytes c*1024 + l*16,
  // i.e. row = c*16 + l/4, k-halfs offset = (l&3)*8.
  const int srow = lane >> 2;
  const int skh = (lane & 3) * 8;
  const size_t abase = (size_t)(bm * 128) * HB;
  const size_t bbase = (size_t)(bn * 128) * HB;

  const int mrow = lane & 15;
  const int quad = lane >> 4;

  for (int k0 = 0; k0 < HB; k0 += 32) {
#pragma unroll
    for (int it = 0; it < 2; ++it) {
      const int chunk = wave * 2 + it;
      const int row = chunk * 16 + srow;
      __builtin_amdgcn_global_load_lds(
          (const __attribute__((address_space(1))) void*)(A + abase + (size_t)row * HB + k0 + skh),
          (__attribute__((address_space(3))) void*)(As + chunk * 512), 16, 0, 0);
      __builtin_amdgcn_global_load_lds(
          (const __attribute__((address_space(1))) void*)(B + bbase + (size_t)row * HB + k0 + skh),
          (__attribute__((address_space(3))) void*)(Bs + chunk * 512), 16, 0, 0);
    }
    __syncthreads();  // drains vmcnt(0): staged data visible

    half8 af[4], bf[4];
#pragma unroll
    for (int i = 0; i < 4; ++i) {
      af[i] = *(const half8*)(As + (wm + i * 16 + mrow) * 32 + quad * 8);
      bf[i] = *(const half8*)(Bs + (wn + i * 16 + mrow) * 32 + quad * 8);
    }
#pragma unroll
    for (int i = 0; i < 4; ++i)
#pragma unroll
      for (int j = 0; j < 4; ++j)
        acc[i][j] = __builtin_amdgcn_mfma_f32_16x16x32_f16(af[i], bf[j], acc[i][j], 0, 0, 0);
    __syncthreads();  // all waves done reading before next-tile restage
  }

  // epilogue: bias + relu, D layout col=lane&15, row=(lane>>4)*4+reg
#pragma unroll
  for (int i = 0; i < 4; ++i) {
#pragma unroll
    for (int j = 0; j < 4; ++j) {
#pragma unroll
      for (int reg = 0; reg < 4; ++reg) {
        const int grow = bm * 128 + wm + i * 16 + quad * 4 + reg;
        const int gcol = bn * 128 + wn + j * 16 + mrow;
        float v = acc[i][j][reg] + bias[grow];
        v = v > 0.f ? v : 0.f;
        Y[(size_t)grow * NPAD + gcol] = v;
      }
    }
  }
}

// ---------------------------------------------------------------------------
// Kernel 4: per-j epilogue. mixed[r][q] (57x57):
//   r=0: 1 at q%7==0 (9 ones)
//   r>=1 (r-1 = c*7+n): q=0 -> (n==6); q>=1 -> y[j,n,7*(7-c)+q-1]
// where y[j,n,p] = Y[j][p*7+n]. d = rsqrt(max(1,rowsum)); out = d_r*mixed*d_q.
// ---------------------------------------------------------------------------
__global__ __launch_bounds__(256) void epilogue_kernel(
    const float* __restrict__ Y, float* __restrict__ out) {
  const int j = blockIdx.x;
  __shared__ float ly[NR];
  __shared__ float dd[NOUT];

  const float* yj = Y + (size_t)j * NPAD;
  for (int i = threadIdx.x; i < NR; i += 256) ly[i] = yj[i];
  __syncthreads();

  if (threadIdx.x < NOUT) {
    const int r = threadIdx.x;
    float s;
    if (r == 0) {
      s = 9.f;
    } else {
      const int c = (r - 1) / 7;
      const int n = (r - 1) % 7;
      const int base = 7 * (7 - c);  // starts[c]
      s = (n == 6) ? 1.f : 0.f;      // mixed[r][0]
#pragma unroll
      for (int p = 0; p < 56; ++p) s += ly[(base + p) * 7 + n];
    }
    s = s < 1.f ? 1.f : s;  // clip(.,1,None)
    dd[r] = rsqrtf(s);
  }
  __syncthreads();

  float* oj = out + (size_t)j * (NOUT * NOUT);
  for (int i = threadIdx.x; i < NOUT * NOUT; i += 256) {
    const int r = i / NOUT;
    const int q = i % NOUT;
    float v;
    if (r == 0) {
      v = (q % 7 == 0) ? dd[0] * dd[q] : 0.f;
    } else {
      const int c = (r - 1) / 7;
      const int n = (r - 1) % 7;
      if (q == 0)
        v = (n == 6) ? dd[r] * dd[0] : 0.f;
      else
        v = dd[r] * ly[(7 * (7 - c) + q - 1) * 7 + n] * dd[q];
    }
    oj[i] = v;
  }
}

// ---------------------------------------------------------------------------
extern "C" void kernel_launch(void* const* d_in, const int* in_sizes, int n_in,
                              void* d_out, int out_size, void* d_ws, size_t ws_size,
                              hipStream_t stream) {
  const float* mat = (const float*)d_in[0];  // (1024,7,7)
  const float* tex = (const float*)d_in[1];  // (1024,15)
  const float* W = (const float*)d_in[2];    // (8192,1024)
  const float* b = (const float*)d_in[3];    // (8192,)
  float* out = (float*)d_out;                // (8192,57,57)

  char* ws = (char*)d_ws;
  _Float16* Xh = (_Float16*)(ws);                                  // 1.5 MB
  _Float16* Wh = (_Float16*)(ws + (size_t)NPAD * HB * 2);          // 16.8 MB
  float* Y = (float*)(ws + (size_t)NPAD * HB * 2 + (size_t)HM * HB * 2);  // 25.2 MB

  prep_x2_kernel<<<NPAD, 256, 0, stream>>>(mat, tex, Xh);
  prep_w_kernel<<<HM * HB / 4 / 256, 256, 0, stream>>>((const float4*)W, (half4v*)Wh);
  gemm_kernel<<<dim3(HM / 128, NPAD / 128), 256, 0, stream>>>(Wh, Xh, b, Y);
  epilogue_kernel<<<HM, 256, 0, stream>>>(Y, out);
}